// Round 1
// baseline (866.484 us; speedup 1.0000x reference)
//
#include <hip/hip_runtime.h>
#include <cstdint>
#include <cstdio>

#define DEVI __device__ __forceinline__

constexpr int TOKS = 8192;
constexpr int HID  = 1024;
constexpr int INTR = 2048;
constexpr int SINT = 1024;
constexpr int NEXP = 8;
constexpr int MAXSLOT = 17408;   // 16384 assignments + 8*127 padding, rounded up

typedef __bf16 bf16x8 __attribute__((ext_vector_type(8)));
typedef float  f32x4  __attribute__((ext_vector_type(4)));

DEVI unsigned short f2bf(float f) {
  unsigned int u = __float_as_uint(f);
  u += 0x7FFFu + ((u >> 16) & 1u);   // round-to-nearest-even
  return (unsigned short)(u >> 16);
}

// async global->LDS, 16B per lane. LDS dest = base + lane*16 (lane-linear);
// global address is per-lane arbitrary (gather OK).
DEVI void gl_lds16(const unsigned short* g, unsigned short* l) {
  __attribute__((address_space(1))) uint32_t* gp =
      (__attribute__((address_space(1))) uint32_t*)(uintptr_t)g;
  __attribute__((address_space(3))) uint32_t* lp =
      (__attribute__((address_space(3))) uint32_t*)(uint32_t)(uintptr_t)l;
  __builtin_amdgcn_global_load_lds(gp, lp, 16, 0, 0);
}

DEVI float gelu_exact(float v) {
  return 0.5f * v * (1.0f + erff(v * 0.7071067811865475f));
}

// ---------------- fp32 -> bf16 convert ----------------
__global__ void k_f2bf(const float* __restrict__ src, unsigned short* __restrict__ dst, int n4) {
  int i = blockIdx.x * blockDim.x + threadIdx.x;
  const int stride = gridDim.x * blockDim.x;
  for (; i < n4; i += stride) {
    float4 v = ((const float4*)src)[i];
    ushort4 o;
    o.x = f2bf(v.x); o.y = f2bf(v.y); o.z = f2bf(v.z); o.w = f2bf(v.w);
    ((ushort4*)dst)[i] = o;
  }
}

// ---------------- router: fp32 logits, top-2, softmax, slot alloc ----------------
__global__ __launch_bounds__(256) void k_router(
    const float* __restrict__ x, const float* __restrict__ wg,
    unsigned short* __restrict__ xb,
    int* __restrict__ cnt, int* __restrict__ rec_e,
    int* __restrict__ rec_p, float2* __restrict__ rec_g) {
  const int wave = threadIdx.x >> 6;
  const int lane = threadIdx.x & 63;
  const int t = blockIdx.x * 4 + wave;

  float4 xv[4];
  const float4* x4 = (const float4*)(x + (size_t)t * HID);
#pragma unroll
  for (int j = 0; j < 4; ++j) xv[j] = x4[j * 64 + lane];

  // emit bf16 copy of x
  ushort4* xb4 = (ushort4*)(xb + (size_t)t * HID);
#pragma unroll
  for (int j = 0; j < 4; ++j) {
    float4 v = xv[j];
    ushort4 o; o.x = f2bf(v.x); o.y = f2bf(v.y); o.z = f2bf(v.z); o.w = f2bf(v.w);
    xb4[j * 64 + lane] = o;
  }

  float lg[NEXP];
#pragma unroll
  for (int e = 0; e < NEXP; ++e) {
    const float4* w4 = (const float4*)(wg + (size_t)e * HID);
    float s = 0.f;
#pragma unroll
    for (int j = 0; j < 4; ++j) {
      float4 a = xv[j], b = w4[j * 64 + lane];
      s += a.x * b.x + a.y * b.y + a.z * b.z + a.w * b.w;
    }
    lg[e] = s;
  }
#pragma unroll
  for (int e = 0; e < NEXP; ++e)
#pragma unroll
    for (int off = 32; off > 0; off >>= 1) lg[e] += __shfl_xor(lg[e], off);

  if (lane == 0) {
    int b0 = 0; float v0 = lg[0];
    for (int e = 1; e < NEXP; ++e) if (lg[e] > v0) { v0 = lg[e]; b0 = e; }
    int b1 = -1; float v1 = -1e30f;
    for (int e = 0; e < NEXP; ++e) if (e != b0 && lg[e] > v1) { v1 = lg[e]; b1 = e; }
    const float d = expf(v1 - v0);
    const float g0 = 1.f / (1.f + d);
    const float g1 = d / (1.f + d);
    const int p0 = atomicAdd(&cnt[b0], 1);
    const int p1 = atomicAdd(&cnt[b1], 1);
    rec_e[t] = b0 | (b1 << 16);
    rec_p[t] = p0 | (p1 << 16);
    rec_g[t] = make_float2(g0, g1);
  }
}

// ---------------- scan: 128-padded offsets ----------------
__global__ void k_scan(const int* __restrict__ cnt, int* __restrict__ offs) {
  if (threadIdx.x == 0 && blockIdx.x == 0) {
    int o = 0;
    for (int e = 0; e < NEXP; ++e) {
      offs[e] = o;
      o += ((cnt[e] + 127) >> 7) << 7;
    }
    offs[NEXP] = o;
  }
}

// ---------------- assign: fill slot arrays ----------------
__global__ void k_assign(const int* __restrict__ rec_e, const int* __restrict__ rec_p,
                         const float2* __restrict__ rec_g, const int* __restrict__ offs,
                         int* __restrict__ tok, float* __restrict__ gt) {
  const int t = blockIdx.x * 256 + threadIdx.x;
  if (t >= TOKS) return;
  const int ee = rec_e[t], pp = rec_p[t];
  const float2 g = rec_g[t];
  const int s0 = offs[ee & 0xffff] + (pp & 0xffff);
  const int s1 = offs[ee >> 16] + (pp >> 16);
  tok[s0] = t; gt[s0] = g.x;
  tok[s1] = t; gt[s1] = g.y;
}

// ---------------- GEMM: C[m,n] = sum_k A[m,k]*B[n,k]  (B row-major [N,K]) ----------------
// MODE 0: expert fc   (A = gathered x rows, epilogue gelu -> h bf16)
// MODE 1: expert proj (A = h rows, epilogue gate*v atomicAdd scatter -> out)
// MODE 2: shared fc   (A = x, epilogue gelu -> hs bf16)
// MODE 3: shared proj (A = hs, epilogue out += v)
template <int MODE>
__global__ __launch_bounds__(256, 2) void k_gemm(
    const unsigned short* __restrict__ A,
    const unsigned short* __restrict__ B,
    unsigned short* __restrict__ Hout,
    float* __restrict__ Out,
    const int* __restrict__ cnt,
    const int* __restrict__ offs,
    const int* __restrict__ tok,
    const float* __restrict__ gt,
    int K, int N) {
  const int e = blockIdx.z;
  int count, off;
  if (MODE == 0 || MODE == 1) {
    count = cnt[e];
    off = offs[e];
  } else {
    count = TOKS;
    off = 0;
  }
  const int Mpad = (count + 127) & ~127;
  const int m0 = blockIdx.x * 128;
  if (m0 >= Mpad) return;
  const int n0 = blockIdx.y * 128;

  __shared__ alignas(16) unsigned short As[128 * 32];
  __shared__ alignas(16) unsigned short Bs[128 * 32];

  const int tid = threadIdx.x;
  const int wave = tid >> 6;
  const int lane = tid & 63;
  const int srow = lane >> 2;  // staging row within 16-row group
  const int sch  = lane & 3;   // 16B chunk within 64B row

  const unsigned short* Bexp = B + ((MODE <= 1) ? (size_t)e * N * K : (size_t)0);

  const unsigned short* gA[2];
  const unsigned short* gB[2];
  unsigned short* lA[2];
  unsigned short* lB[2];
#pragma unroll
  for (int i = 0; i < 2; ++i) {
    const int r = wave * 32 + i * 16 + srow;  // 0..127
    size_t arow;
    if (MODE == 0) {
      int mr = m0 + r;
      if (mr > count - 1) mr = count - 1;  // clamp into valid slots
      arow = (size_t)tok[off + mr] * (size_t)K;
    } else if (MODE == 1) {
      arow = (size_t)(off + m0 + r) * (size_t)K;
    } else {
      arow = (size_t)(m0 + r) * (size_t)K;
    }
    gA[i] = A + arow + sch * 8;
    gB[i] = Bexp + (size_t)(n0 + r) * (size_t)K + sch * 8;
    lA[i] = &As[(wave * 32 + i * 16) * 32];
    lB[i] = &Bs[(wave * 32 + i * 16) * 32];
  }

  f32x4 acc[4][4] = {};
  const int wm = (wave >> 1) * 64;
  const int wn = (wave & 1) * 64;
  const int fm = lane & 15;
  const int fq = lane >> 4;

  for (int k0 = 0; k0 < K; k0 += 32) {
    gl_lds16(gA[0] + k0, lA[0]);
    gl_lds16(gA[1] + k0, lA[1]);
    gl_lds16(gB[0] + k0, lB[0]);
    gl_lds16(gB[1] + k0, lB[1]);
    __syncthreads();  // drains vmcnt before barrier
    bf16x8 af[4], bfr[4];
#pragma unroll
    for (int i = 0; i < 4; ++i)
      af[i] = *(const bf16x8*)&As[(wm + i * 16 + fm) * 32 + fq * 8];
#pragma unroll
    for (int i = 0; i < 4; ++i)
      bfr[i] = *(const bf16x8*)&Bs[(wn + i * 16 + fm) * 32 + fq * 8];
#pragma unroll
    for (int i = 0; i < 4; ++i)
#pragma unroll
      for (int j = 0; j < 4; ++j)
        acc[i][j] = __builtin_amdgcn_mfma_f32_16x16x32_bf16(af[i], bfr[j], acc[i][j], 0, 0, 0);
    __syncthreads();
  }

#pragma unroll
  for (int i = 0; i < 4; ++i) {
#pragma unroll
    for (int j = 0; j < 4; ++j) {
#pragma unroll
      for (int r = 0; r < 4; ++r) {
        const int m = wm + i * 16 + fq * 4 + r;   // C/D: row = quad*4 + reg
        const int n = wn + j * 16 + fm;           //      col = lane & 15
        const float v = acc[i][j][r];
        if (MODE == 0) {
          Hout[(size_t)(off + m0 + m) * N + (n0 + n)] = f2bf(gelu_exact(v));
        } else if (MODE == 2) {
          Hout[(size_t)(m0 + m) * N + (n0 + n)] = f2bf(gelu_exact(v));
        } else if (MODE == 1) {
          const int mr = m0 + m;
          if (mr < count) {
            const int tt = tok[off + mr];
            const float g = gt[off + mr];
            atomicAdd(&Out[(size_t)tt * N + (n0 + n)], g * v);
          }
        } else {
          Out[(size_t)(m0 + m) * N + (n0 + n)] += v;
        }
      }
    }
  }
}

extern "C" void kernel_launch(void* const* d_in, const int* in_sizes, int n_in,
                              void* d_out, int out_size, void* d_ws, size_t ws_size,
                              hipStream_t stream) {
  const float* x   = (const float*)d_in[0];
  const float* wg  = (const float*)d_in[1];
  const float* wfc = (const float*)d_in[2];
  const float* wpj = (const float*)d_in[3];
  const float* wfs = (const float*)d_in[4];
  const float* wps = (const float*)d_in[5];
  float* out = (float*)d_out;
  char* ws = (char*)d_ws;

  // workspace layout (bytes)
  constexpr size_t OFF_XB   = 0;                                  // 8192*1024*2   = 16,777,216
  constexpr size_t OFF_WFC  = OFF_XB   + (size_t)TOKS * HID * 2;  // 8*2048*1024*2 = 33,554,432
  constexpr size_t OFF_WPJ  = OFF_WFC  + (size_t)NEXP * INTR * HID * 2;
  constexpr size_t OFF_WFS  = OFF_WPJ  + (size_t)NEXP * HID * INTR * 2;  // 2,097,152
  constexpr size_t OFF_WPS  = OFF_WFS  + (size_t)SINT * HID * 2;
  constexpr size_t OFF_H    = OFF_WPS  + (size_t)HID * SINT * 2;  // 17408*2048*2 = 71,303,168
  constexpr size_t OFF_HS   = OFF_H    + (size_t)MAXSLOT * INTR * 2;  // 16,777,216
  constexpr size_t OFF_CNT  = OFF_HS   + (size_t)TOKS * SINT * 2;
  constexpr size_t OFF_OFFS = OFF_CNT  + 32;
  constexpr size_t OFF_RECE = OFF_OFFS + 64;
  constexpr size_t OFF_RECP = OFF_RECE + (size_t)TOKS * 4;
  constexpr size_t OFF_RECG = OFF_RECP + (size_t)TOKS * 4;
  constexpr size_t OFF_TOK  = OFF_RECG + (size_t)TOKS * 8;
  constexpr size_t OFF_GT   = OFF_TOK  + (size_t)MAXSLOT * 4;

  unsigned short* xb   = (unsigned short*)(ws + OFF_XB);
  unsigned short* wfcb = (unsigned short*)(ws + OFF_WFC);
  unsigned short* wpjb = (unsigned short*)(ws + OFF_WPJ);
  unsigned short* wfsb = (unsigned short*)(ws + OFF_WFS);
  unsigned short* wpsb = (unsigned short*)(ws + OFF_WPS);
  unsigned short* h    = (unsigned short*)(ws + OFF_H);
  unsigned short* hs   = (unsigned short*)(ws + OFF_HS);
  int*    cnt   = (int*)(ws + OFF_CNT);
  int*    offs  = (int*)(ws + OFF_OFFS);
  int*    rec_e = (int*)(ws + OFF_RECE);
  int*    rec_p = (int*)(ws + OFF_RECP);
  float2* rec_g = (float2*)(ws + OFF_RECG);
  int*    tok   = (int*)(ws + OFF_TOK);
  float*  gt    = (float*)(ws + OFF_GT);

  hipMemsetAsync(out, 0, (size_t)TOKS * HID * sizeof(float), stream);
  hipMemsetAsync(cnt, 0, NEXP * sizeof(int), stream);

  k_f2bf<<<4096, 256, 0, stream>>>(wfc, wfcb, NEXP * INTR * HID / 4);
  k_f2bf<<<4096, 256, 0, stream>>>(wpj, wpjb, NEXP * HID * INTR / 4);
  k_f2bf<<<512, 256, 0, stream>>>(wfs, wfsb, SINT * HID / 4);
  k_f2bf<<<512, 256, 0, stream>>>(wps, wpsb, HID * SINT / 4);

  k_router<<<TOKS / 4, 256, 0, stream>>>(x, wg, xb, cnt, rec_e, rec_p, rec_g);
  k_scan<<<1, 64, 0, stream>>>(cnt, offs);
  k_assign<<<TOKS / 256, 256, 0, stream>>>(rec_e, rec_p, rec_g, offs, tok, gt);

  // expert fc: M<=8192/expert, N=2048, K=1024
  k_gemm<0><<<dim3(64, INTR / 128, NEXP), 256, 0, stream>>>(xb, wfcb, h, nullptr, cnt, offs, tok, gt, HID, INTR);
  // shared fc: M=8192, N=1024, K=1024
  k_gemm<2><<<dim3(TOKS / 128, SINT / 128, 1), 256, 0, stream>>>(xb, wfsb, hs, nullptr, cnt, offs, tok, gt, HID, SINT);
  // expert proj: N=1024, K=2048, atomic scatter into out
  k_gemm<1><<<dim3(64, HID / 128, NEXP), 256, 0, stream>>>(h, wpjb, nullptr, out, cnt, offs, tok, gt, INTR, HID);
  // shared proj: N=1024, K=1024, out += (must run after expert proj; stream-ordered)
  k_gemm<3><<<dim3(TOKS / 128, HID / 128, 1), 256, 0, stream>>>(hs, wpsb, nullptr, out, cnt, offs, tok, gt, SINT, HID);
}

// Round 2
// 762.765 us; speedup vs baseline: 1.1360x; 1.1360x over previous
//
#include <hip/hip_runtime.h>
#include <cstdint>
#include <cstdio>

#define DEVI __device__ __forceinline__

constexpr int TOKS = 8192;
constexpr int HID  = 1024;
constexpr int INTR = 2048;
constexpr int SINT = 1024;
constexpr int NEXP = 8;
constexpr int MAXSLOT = 17408;   // 16384 assignments + 8*127 padding, rounded up

typedef __bf16 bf16x8 __attribute__((ext_vector_type(8)));
typedef float  f32x4  __attribute__((ext_vector_type(4)));

DEVI unsigned short f2bf(float f) {
  unsigned int u = __float_as_uint(f);
  u += 0x7FFFu + ((u >> 16) & 1u);   // round-to-nearest-even
  return (unsigned short)(u >> 16);
}

DEVI float bf2f(unsigned short h) {
  return __uint_as_float((unsigned int)h << 16);
}

// async global->LDS, 16B per lane. LDS dest = base + lane*16 (lane-linear);
// global address is per-lane arbitrary (gather OK).
DEVI void gl_lds16(const unsigned short* g, unsigned short* l) {
  __attribute__((address_space(1))) uint32_t* gp =
      (__attribute__((address_space(1))) uint32_t*)(uintptr_t)g;
  __attribute__((address_space(3))) uint32_t* lp =
      (__attribute__((address_space(3))) uint32_t*)(uint32_t)(uintptr_t)l;
  __builtin_amdgcn_global_load_lds(gp, lp, 16, 0, 0);
}

DEVI float gelu_exact(float v) {
  return 0.5f * v * (1.0f + erff(v * 0.7071067811865475f));
}

// ---------------- fp32 -> bf16 convert ----------------
__global__ void k_f2bf(const float* __restrict__ src, unsigned short* __restrict__ dst, int n4) {
  int i = blockIdx.x * blockDim.x + threadIdx.x;
  const int stride = gridDim.x * blockDim.x;
  for (; i < n4; i += stride) {
    float4 v = ((const float4*)src)[i];
    ushort4 o;
    o.x = f2bf(v.x); o.y = f2bf(v.y); o.z = f2bf(v.z); o.w = f2bf(v.w);
    ((ushort4*)dst)[i] = o;
  }
}

// ---------------- router: fp32 logits, top-2, softmax, slot alloc ----------------
__global__ __launch_bounds__(256) void k_router(
    const float* __restrict__ x, const float* __restrict__ wg,
    unsigned short* __restrict__ xb,
    int* __restrict__ cnt, int* __restrict__ rec_e,
    int* __restrict__ rec_p, float2* __restrict__ rec_g) {
  const int wave = threadIdx.x >> 6;
  const int lane = threadIdx.x & 63;
  const int t = blockIdx.x * 4 + wave;

  float4 xv[4];
  const float4* x4 = (const float4*)(x + (size_t)t * HID);
#pragma unroll
  for (int j = 0; j < 4; ++j) xv[j] = x4[j * 64 + lane];

  // emit bf16 copy of x
  ushort4* xb4 = (ushort4*)(xb + (size_t)t * HID);
#pragma unroll
  for (int j = 0; j < 4; ++j) {
    float4 v = xv[j];
    ushort4 o; o.x = f2bf(v.x); o.y = f2bf(v.y); o.z = f2bf(v.z); o.w = f2bf(v.w);
    xb4[j * 64 + lane] = o;
  }

  float lg[NEXP];
#pragma unroll
  for (int e = 0; e < NEXP; ++e) {
    const float4* w4 = (const float4*)(wg + (size_t)e * HID);
    float s = 0.f;
#pragma unroll
    for (int j = 0; j < 4; ++j) {
      float4 a = xv[j], b = w4[j * 64 + lane];
      s += a.x * b.x + a.y * b.y + a.z * b.z + a.w * b.w;
    }
    lg[e] = s;
  }
#pragma unroll
  for (int e = 0; e < NEXP; ++e)
#pragma unroll
    for (int off = 32; off > 0; off >>= 1) lg[e] += __shfl_xor(lg[e], off);

  if (lane == 0) {
    int b0 = 0; float v0 = lg[0];
    for (int e = 1; e < NEXP; ++e) if (lg[e] > v0) { v0 = lg[e]; b0 = e; }
    int b1 = -1; float v1 = -1e30f;
    for (int e = 0; e < NEXP; ++e) if (e != b0 && lg[e] > v1) { v1 = lg[e]; b1 = e; }
    const float d = expf(v1 - v0);
    const float g0 = 1.f / (1.f + d);
    const float g1 = d / (1.f + d);
    const int p0 = atomicAdd(&cnt[b0], 1);
    const int p1 = atomicAdd(&cnt[b1], 1);
    rec_e[t] = b0 | (b1 << 16);
    rec_p[t] = p0 | (p1 << 16);
    rec_g[t] = make_float2(g0, g1);
  }
}

// ---------------- scan: 128-padded offsets ----------------
__global__ void k_scan(const int* __restrict__ cnt, int* __restrict__ offs) {
  if (threadIdx.x == 0 && blockIdx.x == 0) {
    int o = 0;
    for (int e = 0; e < NEXP; ++e) {
      offs[e] = o;
      o += ((cnt[e] + 127) >> 7) << 7;
    }
    offs[NEXP] = o;
  }
}

// ---------------- assign: fill slot arrays ----------------
__global__ void k_assign(const int* __restrict__ rec_e, const int* __restrict__ rec_p,
                         const float2* __restrict__ rec_g, const int* __restrict__ offs,
                         int* __restrict__ tok, float* __restrict__ gt) {
  const int t = blockIdx.x * 256 + threadIdx.x;
  if (t >= TOKS) return;
  const int ee = rec_e[t], pp = rec_p[t];
  const float2 g = rec_g[t];
  const int s0 = offs[ee & 0xffff] + (pp & 0xffff);
  const int s1 = offs[ee >> 16] + (pp >> 16);
  tok[s0] = t; gt[s0] = g.x;
  tok[s1] = t; gt[s1] = g.y;
}

// ---------------- GEMM: C[m,n] = sum_k A[m,k]*B[n,k]  (B row-major [N,K]) ----------------
// All modes write bf16 to Hout; gating/combining is a separate pass.
// MODE 0: expert fc   (A = gathered x rows via tok[], gelu) -> h[slot, INTR]
// MODE 1: expert proj (A = h rows, raw)                     -> Y[slot, HID]
// MODE 2: shared fc   (A = x, gelu)                         -> hs[t, SINT]
// MODE 3: shared proj (A = hs, raw)                         -> Ys[t, HID]
template <int MODE>
__global__ __launch_bounds__(256, 2) void k_gemm(
    const unsigned short* __restrict__ A,
    const unsigned short* __restrict__ B,
    unsigned short* __restrict__ Hout,
    const int* __restrict__ cnt,
    const int* __restrict__ offs,
    const int* __restrict__ tok,
    int K, int N) {
  const int e = blockIdx.z;
  int count, off;
  if (MODE == 0 || MODE == 1) {
    count = cnt[e];
    off = offs[e];
  } else {
    count = TOKS;
    off = 0;
  }
  const int Mpad = (count + 127) & ~127;
  const int m0 = blockIdx.x * 128;
  if (m0 >= Mpad) return;
  const int n0 = blockIdx.y * 128;

  __shared__ alignas(16) unsigned short As[128 * 32];
  __shared__ alignas(16) unsigned short Bs[128 * 32];

  const int tid = threadIdx.x;
  const int wave = tid >> 6;
  const int lane = tid & 63;
  const int srow = lane >> 2;  // staging row within 16-row group
  const int sch  = lane & 3;   // 16B chunk within 64B row

  const unsigned short* Bexp = B + ((MODE <= 1) ? (size_t)e * N * K : (size_t)0);

  const unsigned short* gA[2];
  const unsigned short* gB[2];
  unsigned short* lA[2];
  unsigned short* lB[2];
#pragma unroll
  for (int i = 0; i < 2; ++i) {
    const int r = wave * 32 + i * 16 + srow;  // 0..127
    size_t arow;
    if (MODE == 0) {
      int mr = m0 + r;
      if (mr > count - 1) mr = count - 1;  // clamp into valid slots
      arow = (size_t)tok[off + mr] * (size_t)K;
    } else if (MODE == 1) {
      arow = (size_t)(off + m0 + r) * (size_t)K;
    } else {
      arow = (size_t)(m0 + r) * (size_t)K;
    }
    gA[i] = A + arow + sch * 8;
    gB[i] = Bexp + (size_t)(n0 + r) * (size_t)K + sch * 8;
    lA[i] = &As[(wave * 32 + i * 16) * 32];
    lB[i] = &Bs[(wave * 32 + i * 16) * 32];
  }

  f32x4 acc[4][4] = {};
  const int wm = (wave >> 1) * 64;
  const int wn = (wave & 1) * 64;
  const int fm = lane & 15;
  const int fq = lane >> 4;

  for (int k0 = 0; k0 < K; k0 += 32) {
    gl_lds16(gA[0] + k0, lA[0]);
    gl_lds16(gA[1] + k0, lA[1]);
    gl_lds16(gB[0] + k0, lB[0]);
    gl_lds16(gB[1] + k0, lB[1]);
    __syncthreads();  // drains vmcnt before barrier
    bf16x8 af[4], bfr[4];
#pragma unroll
    for (int i = 0; i < 4; ++i)
      af[i] = *(const bf16x8*)&As[(wm + i * 16 + fm) * 32 + fq * 8];
#pragma unroll
    for (int i = 0; i < 4; ++i)
      bfr[i] = *(const bf16x8*)&Bs[(wn + i * 16 + fm) * 32 + fq * 8];
#pragma unroll
    for (int i = 0; i < 4; ++i)
#pragma unroll
      for (int j = 0; j < 4; ++j)
        acc[i][j] = __builtin_amdgcn_mfma_f32_16x16x32_bf16(af[i], bfr[j], acc[i][j], 0, 0, 0);
    __syncthreads();
  }

  constexpr bool GELU = (MODE == 0 || MODE == 2);
#pragma unroll
  for (int i = 0; i < 4; ++i) {
#pragma unroll
    for (int j = 0; j < 4; ++j) {
#pragma unroll
      for (int r = 0; r < 4; ++r) {
        const int m = wm + i * 16 + fq * 4 + r;   // C/D: row = quad*4 + reg
        const int n = wn + j * 16 + fm;           //      col = lane & 15
        const float v = acc[i][j][r];
        Hout[(size_t)(off + m0 + m) * N + (n0 + n)] = f2bf(GELU ? gelu_exact(v) : v);
      }
    }
  }
}

// ---------------- combine: out[t] = g0*Y[s0] + g1*Y[s1] + Ys[t] ----------------
__global__ __launch_bounds__(256) void k_combine(
    const unsigned short* __restrict__ Y,   // [MAXSLOT, HID] bf16
    const unsigned short* __restrict__ Ys,  // [TOKS, HID] bf16
    const int* __restrict__ rec_e, const int* __restrict__ rec_p,
    const float2* __restrict__ rec_g, const int* __restrict__ offs,
    float* __restrict__ out) {
  const int t = blockIdx.x;
  const int ee = rec_e[t], pp = rec_p[t];
  const float2 g = rec_g[t];
  const int s0 = offs[ee & 0xffff] + (pp & 0xffff);
  const int s1 = offs[ee >> 16] + (pp >> 16);
  const int c = threadIdx.x * 4;
  ushort4 a = *(const ushort4*)&Y[(size_t)s0 * HID + c];
  ushort4 b = *(const ushort4*)&Y[(size_t)s1 * HID + c];
  ushort4 s = *(const ushort4*)&Ys[(size_t)t * HID + c];
  float4 o;
  o.x = g.x * bf2f(a.x) + g.y * bf2f(b.x) + bf2f(s.x);
  o.y = g.x * bf2f(a.y) + g.y * bf2f(b.y) + bf2f(s.y);
  o.z = g.x * bf2f(a.z) + g.y * bf2f(b.z) + bf2f(s.z);
  o.w = g.x * bf2f(a.w) + g.y * bf2f(b.w) + bf2f(s.w);
  *(float4*)&out[(size_t)t * HID + c] = o;
}

extern "C" void kernel_launch(void* const* d_in, const int* in_sizes, int n_in,
                              void* d_out, int out_size, void* d_ws, size_t ws_size,
                              hipStream_t stream) {
  const float* x   = (const float*)d_in[0];
  const float* wg  = (const float*)d_in[1];
  const float* wfc = (const float*)d_in[2];
  const float* wpj = (const float*)d_in[3];
  const float* wfs = (const float*)d_in[4];
  const float* wps = (const float*)d_in[5];
  float* out = (float*)d_out;
  char* ws = (char*)d_ws;

  // workspace layout (bytes)
  constexpr size_t OFF_XB   = 0;                                  // 16.78 MB
  constexpr size_t OFF_WFC  = OFF_XB   + (size_t)TOKS * HID * 2;  // 33.55 MB
  constexpr size_t OFF_WPJ  = OFF_WFC  + (size_t)NEXP * INTR * HID * 2;  // 33.55 MB
  constexpr size_t OFF_WFS  = OFF_WPJ  + (size_t)NEXP * HID * INTR * 2;  // 2.10 MB
  constexpr size_t OFF_WPS  = OFF_WFS  + (size_t)SINT * HID * 2;  // 2.10 MB
  constexpr size_t OFF_H    = OFF_WPS  + (size_t)HID * SINT * 2;  // 71.30 MB
  constexpr size_t OFF_HS   = OFF_H    + (size_t)MAXSLOT * INTR * 2;  // 16.78 MB
  constexpr size_t OFF_Y    = OFF_HS   + (size_t)TOKS * SINT * 2;  // 35.65 MB
  constexpr size_t OFF_YS   = OFF_Y    + (size_t)MAXSLOT * HID * 2;  // 16.78 MB
  constexpr size_t OFF_CNT  = OFF_YS   + (size_t)TOKS * HID * 2;
  constexpr size_t OFF_OFFS = OFF_CNT  + 32;
  constexpr size_t OFF_RECE = OFF_OFFS + 64;
  constexpr size_t OFF_RECP = OFF_RECE + (size_t)TOKS * 4;
  constexpr size_t OFF_RECG = OFF_RECP + (size_t)TOKS * 4;
  constexpr size_t OFF_TOK  = OFF_RECG + (size_t)TOKS * 8;
  constexpr size_t OFF_GT   = OFF_TOK  + (size_t)MAXSLOT * 4;
  // total ~229 MB

  unsigned short* xb   = (unsigned short*)(ws + OFF_XB);
  unsigned short* wfcb = (unsigned short*)(ws + OFF_WFC);
  unsigned short* wpjb = (unsigned short*)(ws + OFF_WPJ);
  unsigned short* wfsb = (unsigned short*)(ws + OFF_WFS);
  unsigned short* wpsb = (unsigned short*)(ws + OFF_WPS);
  unsigned short* h    = (unsigned short*)(ws + OFF_H);
  unsigned short* hs   = (unsigned short*)(ws + OFF_HS);
  unsigned short* Y    = (unsigned short*)(ws + OFF_Y);
  unsigned short* Ys   = (unsigned short*)(ws + OFF_YS);
  int*    cnt   = (int*)(ws + OFF_CNT);
  int*    offs  = (int*)(ws + OFF_OFFS);
  int*    rec_e = (int*)(ws + OFF_RECE);
  int*    rec_p = (int*)(ws + OFF_RECP);
  float2* rec_g = (float2*)(ws + OFF_RECG);
  int*    tok   = (int*)(ws + OFF_TOK);
  float*  gt    = (float*)(ws + OFF_GT);
  (void)gt;

  hipMemsetAsync(cnt, 0, NEXP * sizeof(int), stream);

  k_f2bf<<<4096, 256, 0, stream>>>(wfc, wfcb, NEXP * INTR * HID / 4);
  k_f2bf<<<4096, 256, 0, stream>>>(wpj, wpjb, NEXP * HID * INTR / 4);
  k_f2bf<<<512, 256, 0, stream>>>(wfs, wfsb, SINT * HID / 4);
  k_f2bf<<<512, 256, 0, stream>>>(wps, wpsb, HID * SINT / 4);

  k_router<<<TOKS / 4, 256, 0, stream>>>(x, wg, xb, cnt, rec_e, rec_p, rec_g);
  k_scan<<<1, 64, 0, stream>>>(cnt, offs);
  k_assign<<<TOKS / 256, 256, 0, stream>>>(rec_e, rec_p, rec_g, offs, tok, gt);

  // expert fc: M<=8192/expert, N=2048, K=1024 -> h (gelu)
  k_gemm<0><<<dim3(64, INTR / 128, NEXP), 256, 0, stream>>>(xb, wfcb, h, cnt, offs, tok, HID, INTR);
  // shared fc: M=8192, N=1024, K=1024 -> hs (gelu)
  k_gemm<2><<<dim3(TOKS / 128, SINT / 128, 1), 256, 0, stream>>>(xb, wfsb, hs, cnt, offs, tok, HID, SINT);
  // expert proj: N=1024, K=2048 -> Y (raw bf16, per-slot)
  k_gemm<1><<<dim3(64, HID / 128, NEXP), 256, 0, stream>>>(h, wpjb, Y, cnt, offs, tok, INTR, HID);
  // shared proj: N=1024, K=1024 -> Ys (raw bf16)
  k_gemm<3><<<dim3(TOKS / 128, HID / 128, 1), 256, 0, stream>>>(hs, wpsb, Ys, cnt, offs, tok, SINT, HID);

  // final combine: out[t] = g0*Y[s0] + g1*Y[s1] + Ys[t]
  k_combine<<<TOKS, 256, 0, stream>>>(Y, Ys, rec_e, rec_p, rec_g, offs, out);
}

// Round 3
// 596.753 us; speedup vs baseline: 1.4520x; 1.2782x over previous
//
#include <hip/hip_runtime.h>
#include <cstdint>
#include <cstdio>

#define DEVI __device__ __forceinline__

constexpr int TOKS = 8192;
constexpr int HID  = 1024;
constexpr int INTR = 2048;
constexpr int SINT = 1024;
constexpr int NEXP = 8;
constexpr int MAXSLOT = 17408;   // 16384 assignments + 8*127 padding, rounded up

typedef __bf16 bf16x8 __attribute__((ext_vector_type(8)));
typedef float  f32x4  __attribute__((ext_vector_type(4)));

DEVI unsigned short f2bf(float f) {
  unsigned int u = __float_as_uint(f);
  u += 0x7FFFu + ((u >> 16) & 1u);   // round-to-nearest-even
  return (unsigned short)(u >> 16);
}

DEVI float bf2f(unsigned short h) {
  return __uint_as_float((unsigned int)h << 16);
}

// async global->LDS, 16B per lane. LDS dest = base + lane*16 (lane-linear);
// global address is per-lane arbitrary (gather OK).
DEVI void gl_lds16(const unsigned short* g, unsigned short* l) {
  __attribute__((address_space(1))) uint32_t* gp =
      (__attribute__((address_space(1))) uint32_t*)(uintptr_t)g;
  __attribute__((address_space(3))) uint32_t* lp =
      (__attribute__((address_space(3))) uint32_t*)(uint32_t)(uintptr_t)l;
  __builtin_amdgcn_global_load_lds(gp, lp, 16, 0, 0);
}

DEVI float gelu_exact(float v) {
  return 0.5f * v * (1.0f + erff(v * 0.7071067811865475f));
}

// ---------------- fp32 -> bf16 convert ----------------
__global__ void k_f2bf(const float* __restrict__ src, unsigned short* __restrict__ dst, int n4) {
  int i = blockIdx.x * blockDim.x + threadIdx.x;
  const int stride = gridDim.x * blockDim.x;
  for (; i < n4; i += stride) {
    float4 v = ((const float4*)src)[i];
    ushort4 o;
    o.x = f2bf(v.x); o.y = f2bf(v.y); o.z = f2bf(v.z); o.w = f2bf(v.w);
    ((ushort4*)dst)[i] = o;
  }
}

// ---------------- router: fp32 logits, top-2, softmax. NO ATOMICS. ----------------
__global__ __launch_bounds__(256) void k_router(
    const float* __restrict__ x, const float* __restrict__ wg,
    unsigned short* __restrict__ xb,
    int* __restrict__ rec_e, float2* __restrict__ rec_g) {
  const int wave = threadIdx.x >> 6;
  const int lane = threadIdx.x & 63;
  const int t = blockIdx.x * 4 + wave;

  float4 xv[4];
  const float4* x4 = (const float4*)(x + (size_t)t * HID);
#pragma unroll
  for (int j = 0; j < 4; ++j) xv[j] = x4[j * 64 + lane];

  // emit bf16 copy of x
  ushort4* xb4 = (ushort4*)(xb + (size_t)t * HID);
#pragma unroll
  for (int j = 0; j < 4; ++j) {
    float4 v = xv[j];
    ushort4 o; o.x = f2bf(v.x); o.y = f2bf(v.y); o.z = f2bf(v.z); o.w = f2bf(v.w);
    xb4[j * 64 + lane] = o;
  }

  float lg[NEXP];
#pragma unroll
  for (int e = 0; e < NEXP; ++e) {
    const float4* w4 = (const float4*)(wg + (size_t)e * HID);
    float s = 0.f;
#pragma unroll
    for (int j = 0; j < 4; ++j) {
      float4 a = xv[j], b = w4[j * 64 + lane];
      s += a.x * b.x + a.y * b.y + a.z * b.z + a.w * b.w;
    }
    lg[e] = s;
  }
#pragma unroll
  for (int e = 0; e < NEXP; ++e)
#pragma unroll
    for (int off = 32; off > 0; off >>= 1) lg[e] += __shfl_xor(lg[e], off);

  if (lane == 0) {
    int b0 = 0; float v0 = lg[0];
    for (int e = 1; e < NEXP; ++e) if (lg[e] > v0) { v0 = lg[e]; b0 = e; }
    int b1 = -1; float v1 = -1e30f;
    for (int e = 0; e < NEXP; ++e) if (e != b0 && lg[e] > v1) { v1 = lg[e]; b1 = e; }
    const float d = expf(v1 - v0);
    const float g0 = 1.f / (1.f + d);
    const float g1 = d / (1.f + d);
    rec_e[t] = b0 | (b1 << 16);
    rec_g[t] = make_float2(g0, g1);
  }
}

// ---------------- count: hierarchical rank-within-expert (LDS hist + 8 global atomics/block) ----------------
__global__ __launch_bounds__(256) void k_count(
    const int* __restrict__ rec_e, int* __restrict__ rec_p, int* __restrict__ cnt) {
  __shared__ int hist[NEXP];
  __shared__ int base[NEXP];
  const int t = blockIdx.x * 256 + threadIdx.x;
  if (threadIdx.x < NEXP) hist[threadIdx.x] = 0;
  __syncthreads();
  const int ee = rec_e[t];
  const int e0 = ee & 0xffff, e1 = ee >> 16;
  const int r0 = atomicAdd(&hist[e0], 1);   // LDS atomic: intra-block rank
  const int r1 = atomicAdd(&hist[e1], 1);
  __syncthreads();
  if (threadIdx.x < NEXP)
    base[threadIdx.x] = atomicAdd(&cnt[threadIdx.x], hist[threadIdx.x]);  // 8 global atomics/block
  __syncthreads();
  rec_p[t] = (base[e0] + r0) | ((base[e1] + r1) << 16);
}

// ---------------- scan: 128-padded offsets ----------------
__global__ void k_scan(const int* __restrict__ cnt, int* __restrict__ offs) {
  if (threadIdx.x == 0 && blockIdx.x == 0) {
    int o = 0;
    for (int e = 0; e < NEXP; ++e) {
      offs[e] = o;
      o += ((cnt[e] + 127) >> 7) << 7;
    }
    offs[NEXP] = o;
  }
}

// ---------------- assign: fill slot arrays ----------------
__global__ void k_assign(const int* __restrict__ rec_e, const int* __restrict__ rec_p,
                         const int* __restrict__ offs, int* __restrict__ tok) {
  const int t = blockIdx.x * 256 + threadIdx.x;
  if (t >= TOKS) return;
  const int ee = rec_e[t], pp = rec_p[t];
  const int s0 = offs[ee & 0xffff] + (pp & 0xffff);
  const int s1 = offs[ee >> 16] + (pp >> 16);
  tok[s0] = t;
  tok[s1] = t;
}

// ---------------- GEMM: C[m,n] = sum_k A[m,k]*B[n,k]  (B row-major [N,K]) ----------------
// All modes write bf16 to Hout; gating/combining is a separate pass.
// MODE 0: expert fc   (A = gathered x rows via tok[], gelu) -> h[slot, INTR]
// MODE 1: expert proj (A = h rows, raw)                     -> Y[slot, HID]
// MODE 2: shared fc   (A = x, gelu)                         -> hs[t, SINT]
// MODE 3: shared proj (A = hs, raw)                         -> Ys[t, HID]
template <int MODE>
__global__ __launch_bounds__(256, 2) void k_gemm(
    const unsigned short* __restrict__ A,
    const unsigned short* __restrict__ B,
    unsigned short* __restrict__ Hout,
    const int* __restrict__ cnt,
    const int* __restrict__ offs,
    const int* __restrict__ tok,
    int K, int N) {
  const int e = blockIdx.z;
  int count, off;
  if (MODE == 0 || MODE == 1) {
    count = cnt[e];
    off = offs[e];
  } else {
    count = TOKS;
    off = 0;
  }
  const int Mpad = (count + 127) & ~127;
  const int m0 = blockIdx.x * 128;
  if (m0 >= Mpad) return;
  const int n0 = blockIdx.y * 128;

  __shared__ alignas(16) unsigned short As[128 * 32];
  __shared__ alignas(16) unsigned short Bs[128 * 32];

  const int tid = threadIdx.x;
  const int wave = tid >> 6;
  const int lane = tid & 63;
  const int srow = lane >> 2;  // staging row within 16-row group
  const int sch  = lane & 3;   // 16B chunk within 64B row

  const unsigned short* Bexp = B + ((MODE <= 1) ? (size_t)e * N * K : (size_t)0);

  const unsigned short* gA[2];
  const unsigned short* gB[2];
  unsigned short* lA[2];
  unsigned short* lB[2];
#pragma unroll
  for (int i = 0; i < 2; ++i) {
    const int r = wave * 32 + i * 16 + srow;  // 0..127
    size_t arow;
    if (MODE == 0) {
      int mr = m0 + r;
      if (mr > count - 1) mr = count - 1;  // clamp into valid slots
      arow = (size_t)tok[off + mr] * (size_t)K;
    } else if (MODE == 1) {
      arow = (size_t)(off + m0 + r) * (size_t)K;
    } else {
      arow = (size_t)(m0 + r) * (size_t)K;
    }
    gA[i] = A + arow + sch * 8;
    gB[i] = Bexp + (size_t)(n0 + r) * (size_t)K + sch * 8;
    lA[i] = &As[(wave * 32 + i * 16) * 32];
    lB[i] = &Bs[(wave * 32 + i * 16) * 32];
  }

  f32x4 acc[4][4] = {};
  const int wm = (wave >> 1) * 64;
  const int wn = (wave & 1) * 64;
  const int fm = lane & 15;
  const int fq = lane >> 4;

  for (int k0 = 0; k0 < K; k0 += 32) {
    gl_lds16(gA[0] + k0, lA[0]);
    gl_lds16(gA[1] + k0, lA[1]);
    gl_lds16(gB[0] + k0, lB[0]);
    gl_lds16(gB[1] + k0, lB[1]);
    __syncthreads();  // drains vmcnt before barrier
    bf16x8 af[4], bfr[4];
#pragma unroll
    for (int i = 0; i < 4; ++i)
      af[i] = *(const bf16x8*)&As[(wm + i * 16 + fm) * 32 + fq * 8];
#pragma unroll
    for (int i = 0; i < 4; ++i)
      bfr[i] = *(const bf16x8*)&Bs[(wn + i * 16 + fm) * 32 + fq * 8];
#pragma unroll
    for (int i = 0; i < 4; ++i)
#pragma unroll
      for (int j = 0; j < 4; ++j)
        acc[i][j] = __builtin_amdgcn_mfma_f32_16x16x32_bf16(af[i], bfr[j], acc[i][j], 0, 0, 0);
    __syncthreads();
  }

  constexpr bool GELU = (MODE == 0 || MODE == 2);
#pragma unroll
  for (int i = 0; i < 4; ++i) {
#pragma unroll
    for (int j = 0; j < 4; ++j) {
#pragma unroll
      for (int r = 0; r < 4; ++r) {
        const int m = wm + i * 16 + fq * 4 + r;   // C/D: row = quad*4 + reg
        const int n = wn + j * 16 + fm;           //      col = lane & 15
        const float v = acc[i][j][r];
        Hout[(size_t)(off + m0 + m) * N + (n0 + n)] = f2bf(GELU ? gelu_exact(v) : v);
      }
    }
  }
}

// ---------------- combine: out[t] = g0*Y[s0] + g1*Y[s1] + Ys[t] ----------------
__global__ __launch_bounds__(256) void k_combine(
    const unsigned short* __restrict__ Y,   // [MAXSLOT, HID] bf16
    const unsigned short* __restrict__ Ys,  // [TOKS, HID] bf16
    const int* __restrict__ rec_e, const int* __restrict__ rec_p,
    const float2* __restrict__ rec_g, const int* __restrict__ offs,
    float* __restrict__ out) {
  const int t = blockIdx.x;
  const int ee = rec_e[t], pp = rec_p[t];
  const float2 g = rec_g[t];
  const int s0 = offs[ee & 0xffff] + (pp & 0xffff);
  const int s1 = offs[ee >> 16] + (pp >> 16);
  const int c = threadIdx.x * 4;
  ushort4 a = *(const ushort4*)&Y[(size_t)s0 * HID + c];
  ushort4 b = *(const ushort4*)&Y[(size_t)s1 * HID + c];
  ushort4 s = *(const ushort4*)&Ys[(size_t)t * HID + c];
  float4 o;
  o.x = g.x * bf2f(a.x) + g.y * bf2f(b.x) + bf2f(s.x);
  o.y = g.x * bf2f(a.y) + g.y * bf2f(b.y) + bf2f(s.y);
  o.z = g.x * bf2f(a.z) + g.y * bf2f(b.z) + bf2f(s.z);
  o.w = g.x * bf2f(a.w) + g.y * bf2f(b.w) + bf2f(s.w);
  *(float4*)&out[(size_t)t * HID + c] = o;
}

extern "C" void kernel_launch(void* const* d_in, const int* in_sizes, int n_in,
                              void* d_out, int out_size, void* d_ws, size_t ws_size,
                              hipStream_t stream) {
  const float* x   = (const float*)d_in[0];
  const float* wg  = (const float*)d_in[1];
  const float* wfc = (const float*)d_in[2];
  const float* wpj = (const float*)d_in[3];
  const float* wfs = (const float*)d_in[4];
  const float* wps = (const float*)d_in[5];
  float* out = (float*)d_out;
  char* ws = (char*)d_ws;

  // workspace layout (bytes)
  constexpr size_t OFF_XB   = 0;                                  // 16.78 MB
  constexpr size_t OFF_WFC  = OFF_XB   + (size_t)TOKS * HID * 2;  // 33.55 MB
  constexpr size_t OFF_WPJ  = OFF_WFC  + (size_t)NEXP * INTR * HID * 2;  // 33.55 MB
  constexpr size_t OFF_WFS  = OFF_WPJ  + (size_t)NEXP * HID * INTR * 2;  // 2.10 MB
  constexpr size_t OFF_WPS  = OFF_WFS  + (size_t)SINT * HID * 2;  // 2.10 MB
  constexpr size_t OFF_H    = OFF_WPS  + (size_t)HID * SINT * 2;  // 71.30 MB
  constexpr size_t OFF_HS   = OFF_H    + (size_t)MAXSLOT * INTR * 2;  // 16.78 MB
  constexpr size_t OFF_Y    = OFF_HS   + (size_t)TOKS * SINT * 2;  // 35.65 MB
  constexpr size_t OFF_YS   = OFF_Y    + (size_t)MAXSLOT * HID * 2;  // 16.78 MB
  constexpr size_t OFF_CNT  = OFF_YS   + (size_t)TOKS * HID * 2;
  constexpr size_t OFF_OFFS = OFF_CNT  + 32;
  constexpr size_t OFF_RECE = OFF_OFFS + 64;
  constexpr size_t OFF_RECP = OFF_RECE + (size_t)TOKS * 4;
  constexpr size_t OFF_RECG = OFF_RECP + (size_t)TOKS * 4;
  constexpr size_t OFF_TOK  = OFF_RECG + (size_t)TOKS * 8;
  // total ~229 MB

  unsigned short* xb   = (unsigned short*)(ws + OFF_XB);
  unsigned short* wfcb = (unsigned short*)(ws + OFF_WFC);
  unsigned short* wpjb = (unsigned short*)(ws + OFF_WPJ);
  unsigned short* wfsb = (unsigned short*)(ws + OFF_WFS);
  unsigned short* wpsb = (unsigned short*)(ws + OFF_WPS);
  unsigned short* h    = (unsigned short*)(ws + OFF_H);
  unsigned short* hs   = (unsigned short*)(ws + OFF_HS);
  unsigned short* Y    = (unsigned short*)(ws + OFF_Y);
  unsigned short* Ys   = (unsigned short*)(ws + OFF_YS);
  int*    cnt   = (int*)(ws + OFF_CNT);
  int*    offs  = (int*)(ws + OFF_OFFS);
  int*    rec_e = (int*)(ws + OFF_RECE);
  int*    rec_p = (int*)(ws + OFF_RECP);
  float2* rec_g = (float2*)(ws + OFF_RECG);
  int*    tok   = (int*)(ws + OFF_TOK);

  hipMemsetAsync(cnt, 0, NEXP * sizeof(int), stream);

  k_f2bf<<<4096, 256, 0, stream>>>(wfc, wfcb, NEXP * INTR * HID / 4);
  k_f2bf<<<4096, 256, 0, stream>>>(wpj, wpjb, NEXP * HID * INTR / 4);
  k_f2bf<<<512, 256, 0, stream>>>(wfs, wfsb, SINT * HID / 4);
  k_f2bf<<<512, 256, 0, stream>>>(wps, wpsb, HID * SINT / 4);

  k_router<<<TOKS / 4, 256, 0, stream>>>(x, wg, xb, rec_e, rec_g);
  k_count<<<TOKS / 256, 256, 0, stream>>>(rec_e, rec_p, cnt);
  k_scan<<<1, 64, 0, stream>>>(cnt, offs);
  k_assign<<<TOKS / 256, 256, 0, stream>>>(rec_e, rec_p, offs, tok);

  // expert fc: M<=8192/expert, N=2048, K=1024 -> h (gelu)
  k_gemm<0><<<dim3(64, INTR / 128, NEXP), 256, 0, stream>>>(xb, wfcb, h, cnt, offs, tok, HID, INTR);
  // shared fc: M=8192, N=1024, K=1024 -> hs (gelu)
  k_gemm<2><<<dim3(TOKS / 128, SINT / 128, 1), 256, 0, stream>>>(xb, wfsb, hs, cnt, offs, tok, HID, SINT);
  // expert proj: N=1024, K=2048 -> Y (raw bf16, per-slot)
  k_gemm<1><<<dim3(64, HID / 128, NEXP), 256, 0, stream>>>(h, wpjb, Y, cnt, offs, tok, INTR, HID);
  // shared proj: N=1024, K=1024 -> Ys (raw bf16)
  k_gemm<3><<<dim3(TOKS / 128, HID / 128, 1), 256, 0, stream>>>(hs, wpsb, Ys, cnt, offs, tok, SINT, HID);

  // final combine: out[t] = g0*Y[s0] + g1*Y[s1] + Ys[t]
  k_combine<<<TOKS, 256, 0, stream>>>(Y, Ys, rec_e, rec_p, rec_g, offs, out);
}

// Round 4
// 554.607 us; speedup vs baseline: 1.5623x; 1.0760x over previous
//
#include <hip/hip_runtime.h>
#include <cstdint>
#include <cstdio>

#define DEVI __device__ __forceinline__

constexpr int TOKS = 8192;
constexpr int HID  = 1024;
constexpr int INTR = 2048;
constexpr int SINT = 1024;
constexpr int NEXP = 8;
constexpr int MAXSLOT = 17408;   // 16384 assignments + 8*127 padding, rounded up

typedef __bf16 bf16x8 __attribute__((ext_vector_type(8)));
typedef float  f32x4  __attribute__((ext_vector_type(4)));

DEVI unsigned short f2bf(float f) {
  unsigned int u = __float_as_uint(f);
  u += 0x7FFFu + ((u >> 16) & 1u);   // round-to-nearest-even
  return (unsigned short)(u >> 16);
}

DEVI float bf2f(unsigned short h) {
  return __uint_as_float((unsigned int)h << 16);
}

// async global->LDS, 16B per lane. LDS dest = base + lane*16 (lane-linear);
// global address is per-lane arbitrary (gather OK).
DEVI void gl_lds16(const unsigned short* g, unsigned short* l) {
  __attribute__((address_space(1))) uint32_t* gp =
      (__attribute__((address_space(1))) uint32_t*)(uintptr_t)g;
  __attribute__((address_space(3))) uint32_t* lp =
      (__attribute__((address_space(3))) uint32_t*)(uint32_t)(uintptr_t)l;
  __builtin_amdgcn_global_load_lds(gp, lp, 16, 0, 0);
}

// exact-gelu via Abramowitz-Stegun 7.1.26 erf (|err| <= 1.5e-7), ~14 VALU ops.
DEVI float gelu_fast(float x) {
  const float z = fabsf(x) * 0.70710678118654752f;
  const float t = __builtin_amdgcn_rcpf(1.0f + 0.3275911f * z);
  float p = 1.061405429f;
  p = p * t - 1.453152027f;
  p = p * t + 1.421413741f;
  p = p * t - 0.284496736f;
  p = p * t + 0.254829592f;
  const float e = __builtin_amdgcn_exp2f(-z * z * 1.4426950408889634f);  // exp(-z^2)
  float erfz = 1.0f - p * t * e;     // erf(|z|)
  erfz = copysignf(erfz, x);
  return 0.5f * x * (1.0f + erfz);
}

// ---------------- fused fp32 -> bf16 convert over 4 weight arrays ----------------
__global__ void k_f2bf_all(const float* __restrict__ s0, unsigned short* __restrict__ d0, int n0,
                           const float* __restrict__ s1, unsigned short* __restrict__ d1, int n1,
                           const float* __restrict__ s2, unsigned short* __restrict__ d2, int n2,
                           const float* __restrict__ s3, unsigned short* __restrict__ d3, int n3) {
  const int ntot = n0 + n1 + n2 + n3;
  int i = blockIdx.x * blockDim.x + threadIdx.x;
  const int stride = gridDim.x * blockDim.x;
  for (; i < ntot; i += stride) {
    int j = i;
    const float* s; unsigned short* d;
    if (j < n0) { s = s0; d = d0; }
    else if ((j -= n0) < n1) { s = s1; d = d1; }
    else if ((j -= n1) < n2) { s = s2; d = d2; }
    else { j -= n2; s = s3; d = d3; }
    float4 v = ((const float4*)s)[j];
    ushort4 o;
    o.x = f2bf(v.x); o.y = f2bf(v.y); o.z = f2bf(v.z); o.w = f2bf(v.w);
    ((ushort4*)d)[j] = o;
  }
}

// ---------------- router: fp32 logits, top-2, softmax. NO ATOMICS. ----------------
__global__ __launch_bounds__(256) void k_router(
    const float* __restrict__ x, const float* __restrict__ wg,
    unsigned short* __restrict__ xb,
    int* __restrict__ rec_e, float2* __restrict__ rec_g) {
  const int wave = threadIdx.x >> 6;
  const int lane = threadIdx.x & 63;
  const int t = blockIdx.x * 4 + wave;

  float4 xv[4];
  const float4* x4 = (const float4*)(x + (size_t)t * HID);
#pragma unroll
  for (int j = 0; j < 4; ++j) xv[j] = x4[j * 64 + lane];

  // emit bf16 copy of x
  ushort4* xb4 = (ushort4*)(xb + (size_t)t * HID);
#pragma unroll
  for (int j = 0; j < 4; ++j) {
    float4 v = xv[j];
    ushort4 o; o.x = f2bf(v.x); o.y = f2bf(v.y); o.z = f2bf(v.z); o.w = f2bf(v.w);
    xb4[j * 64 + lane] = o;
  }

  float lg[NEXP];
#pragma unroll
  for (int e = 0; e < NEXP; ++e) {
    const float4* w4 = (const float4*)(wg + (size_t)e * HID);
    float s = 0.f;
#pragma unroll
    for (int j = 0; j < 4; ++j) {
      float4 a = xv[j], b = w4[j * 64 + lane];
      s += a.x * b.x + a.y * b.y + a.z * b.z + a.w * b.w;
    }
    lg[e] = s;
  }
#pragma unroll
  for (int e = 0; e < NEXP; ++e)
#pragma unroll
    for (int off = 32; off > 0; off >>= 1) lg[e] += __shfl_xor(lg[e], off);

  if (lane == 0) {
    int b0 = 0; float v0 = lg[0];
    for (int e = 1; e < NEXP; ++e) if (lg[e] > v0) { v0 = lg[e]; b0 = e; }
    int b1 = -1; float v1 = -1e30f;
    for (int e = 0; e < NEXP; ++e) if (e != b0 && lg[e] > v1) { v1 = lg[e]; b1 = e; }
    const float d = expf(v1 - v0);
    const float g0 = 1.f / (1.f + d);
    const float g1 = d / (1.f + d);
    rec_e[t] = b0 | (b1 << 16);
    rec_g[t] = make_float2(g0, g1);
  }
}

// ---------------- count: hierarchical rank-within-expert (LDS hist + 8 global atomics/block) ----------------
__global__ __launch_bounds__(256) void k_count(
    const int* __restrict__ rec_e, int* __restrict__ rec_p, int* __restrict__ cnt) {
  __shared__ int hist[NEXP];
  __shared__ int base[NEXP];
  const int t = blockIdx.x * 256 + threadIdx.x;
  if (threadIdx.x < NEXP) hist[threadIdx.x] = 0;
  __syncthreads();
  const int ee = rec_e[t];
  const int e0 = ee & 0xffff, e1 = ee >> 16;
  const int r0 = atomicAdd(&hist[e0], 1);   // LDS atomic: intra-block rank
  const int r1 = atomicAdd(&hist[e1], 1);
  __syncthreads();
  if (threadIdx.x < NEXP)
    base[threadIdx.x] = atomicAdd(&cnt[threadIdx.x], hist[threadIdx.x]);  // 8 global atomics/block
  __syncthreads();
  rec_p[t] = (base[e0] + r0) | ((base[e1] + r1) << 16);
}

// ---------------- scan: 128-padded offsets ----------------
__global__ void k_scan(const int* __restrict__ cnt, int* __restrict__ offs) {
  if (threadIdx.x == 0 && blockIdx.x == 0) {
    int o = 0;
    for (int e = 0; e < NEXP; ++e) {
      offs[e] = o;
      o += ((cnt[e] + 127) >> 7) << 7;
    }
    offs[NEXP] = o;
  }
}

// ---------------- assign: fill slot arrays ----------------
__global__ void k_assign(const int* __restrict__ rec_e, const int* __restrict__ rec_p,
                         const int* __restrict__ offs, int* __restrict__ tok) {
  const int t = blockIdx.x * 256 + threadIdx.x;
  if (t >= TOKS) return;
  const int ee = rec_e[t], pp = rec_p[t];
  const int s0 = offs[ee & 0xffff] + (pp & 0xffff);
  const int s1 = offs[ee >> 16] + (pp >> 16);
  tok[s0] = t;
  tok[s1] = t;
}

// ---------------- GEMM: C[m,n] = sum_k A[m,k]*B[n,k]  (B row-major [N,K]) ----------------
// BK=64 via two 32-wide LDS stages per barrier pair (halves barrier drains vs BK=32).
// MODE 0: expert fc   (A = gathered x rows via tok[], gelu) -> h[slot, INTR]
// MODE 1: expert proj (A = h rows, raw)                     -> Y[slot, HID]
// MODE 2: shared fc   (A = x, gelu)                         -> hs[t, SINT]
// MODE 3: shared proj (A = hs, raw)                         -> Ys[t, HID]
template <int MODE>
__global__ __launch_bounds__(256, 2) void k_gemm(
    const unsigned short* __restrict__ A,
    const unsigned short* __restrict__ B,
    unsigned short* __restrict__ Hout,
    const int* __restrict__ cnt,
    const int* __restrict__ offs,
    const int* __restrict__ tok,
    int K, int N) {
  const int e = blockIdx.z;
  int count, off;
  if (MODE == 0 || MODE == 1) {
    count = cnt[e];
    off = offs[e];
  } else {
    count = TOKS;
    off = 0;
  }
  const int Mpad = (count + 127) & ~127;
  const int m0 = blockIdx.x * 128;
  if (m0 >= Mpad) return;
  const int n0 = blockIdx.y * 128;

  // two 32-wide k-stages, each 128 rows x 32 cols bf16 (8 KB); total 32 KB
  __shared__ alignas(16) unsigned short As[2][128 * 32];
  __shared__ alignas(16) unsigned short Bs[2][128 * 32];

  const int tid = threadIdx.x;
  const int wave = tid >> 6;
  const int lane = tid & 63;
  const int srow = lane >> 2;  // staging row within 16-row group
  const int sch  = lane & 3;   // 16B chunk within 64B row

  const unsigned short* Bexp = B + ((MODE <= 1) ? (size_t)e * N * K : (size_t)0);

  const unsigned short* gA[2];
  const unsigned short* gB[2];
  int ldsOff[2];
#pragma unroll
  for (int i = 0; i < 2; ++i) {
    const int r = wave * 32 + i * 16 + srow;  // 0..127
    size_t arow;
    if (MODE == 0) {
      int mr = m0 + r;
      if (mr > count - 1) mr = count - 1;  // clamp into valid slots
      arow = (size_t)tok[off + mr] * (size_t)K;
    } else if (MODE == 1) {
      arow = (size_t)(off + m0 + r) * (size_t)K;
    } else {
      arow = (size_t)(m0 + r) * (size_t)K;
    }
    gA[i] = A + arow + sch * 8;
    gB[i] = Bexp + (size_t)(n0 + r) * (size_t)K + sch * 8;
    ldsOff[i] = (wave * 32 + i * 16) * 32;
  }

  f32x4 acc[4][4] = {};
  const int wm = (wave >> 1) * 64;
  const int wn = (wave & 1) * 64;
  const int fm = lane & 15;
  const int fq = lane >> 4;

  for (int k0 = 0; k0 < K; k0 += 64) {
#pragma unroll
    for (int s = 0; s < 2; ++s) {
      const int ks = k0 + s * 32;
      gl_lds16(gA[0] + ks, &As[s][ldsOff[0]]);
      gl_lds16(gA[1] + ks, &As[s][ldsOff[1]]);
      gl_lds16(gB[0] + ks, &Bs[s][ldsOff[0]]);
      gl_lds16(gB[1] + ks, &Bs[s][ldsOff[1]]);
    }
    __syncthreads();  // drains vmcnt before barrier
#pragma unroll
    for (int s = 0; s < 2; ++s) {
      bf16x8 af[4], bfr[4];
#pragma unroll
      for (int i = 0; i < 4; ++i)
        af[i] = *(const bf16x8*)&As[s][(wm + i * 16 + fm) * 32 + fq * 8];
#pragma unroll
      for (int i = 0; i < 4; ++i)
        bfr[i] = *(const bf16x8*)&Bs[s][(wn + i * 16 + fm) * 32 + fq * 8];
#pragma unroll
      for (int i = 0; i < 4; ++i)
#pragma unroll
        for (int j = 0; j < 4; ++j)
          acc[i][j] = __builtin_amdgcn_mfma_f32_16x16x32_bf16(af[i], bfr[j], acc[i][j], 0, 0, 0);
    }
    __syncthreads();
  }

  constexpr bool GELU = (MODE == 0 || MODE == 2);
#pragma unroll
  for (int i = 0; i < 4; ++i) {
#pragma unroll
    for (int j = 0; j < 4; ++j) {
#pragma unroll
      for (int r = 0; r < 4; ++r) {
        const int m = wm + i * 16 + fq * 4 + r;   // C/D: row = quad*4 + reg
        const int n = wn + j * 16 + fm;           //      col = lane & 15
        const float v = acc[i][j][r];
        Hout[(size_t)(off + m0 + m) * N + (n0 + n)] = f2bf(GELU ? gelu_fast(v) : v);
      }
    }
  }
}

// ---------------- combine: out[t] = g0*Y[s0] + g1*Y[s1] + Ys[t] ----------------
__global__ __launch_bounds__(256) void k_combine(
    const unsigned short* __restrict__ Y,   // [MAXSLOT, HID] bf16
    const unsigned short* __restrict__ Ys,  // [TOKS, HID] bf16
    const int* __restrict__ rec_e, const int* __restrict__ rec_p,
    const float2* __restrict__ rec_g, const int* __restrict__ offs,
    float* __restrict__ out) {
  const int t = blockIdx.x;
  const int ee = rec_e[t], pp = rec_p[t];
  const float2 g = rec_g[t];
  const int s0 = offs[ee & 0xffff] + (pp & 0xffff);
  const int s1 = offs[ee >> 16] + (pp >> 16);
  const int c = threadIdx.x * 4;
  ushort4 a = *(const ushort4*)&Y[(size_t)s0 * HID + c];
  ushort4 b = *(const ushort4*)&Y[(size_t)s1 * HID + c];
  ushort4 s = *(const ushort4*)&Ys[(size_t)t * HID + c];
  float4 o;
  o.x = g.x * bf2f(a.x) + g.y * bf2f(b.x) + bf2f(s.x);
  o.y = g.x * bf2f(a.y) + g.y * bf2f(b.y) + bf2f(s.y);
  o.z = g.x * bf2f(a.z) + g.y * bf2f(b.z) + bf2f(s.z);
  o.w = g.x * bf2f(a.w) + g.y * bf2f(b.w) + bf2f(s.w);
  *(float4*)&out[(size_t)t * HID + c] = o;
}

extern "C" void kernel_launch(void* const* d_in, const int* in_sizes, int n_in,
                              void* d_out, int out_size, void* d_ws, size_t ws_size,
                              hipStream_t stream) {
  const float* x   = (const float*)d_in[0];
  const float* wg  = (const float*)d_in[1];
  const float* wfc = (const float*)d_in[2];
  const float* wpj = (const float*)d_in[3];
  const float* wfs = (const float*)d_in[4];
  const float* wps = (const float*)d_in[5];
  float* out = (float*)d_out;
  char* ws = (char*)d_ws;

  // workspace layout (bytes)
  constexpr size_t OFF_XB   = 0;                                  // 16.78 MB
  constexpr size_t OFF_WFC  = OFF_XB   + (size_t)TOKS * HID * 2;  // 33.55 MB
  constexpr size_t OFF_WPJ  = OFF_WFC  + (size_t)NEXP * INTR * HID * 2;  // 33.55 MB
  constexpr size_t OFF_WFS  = OFF_WPJ  + (size_t)NEXP * HID * INTR * 2;  // 2.10 MB
  constexpr size_t OFF_WPS  = OFF_WFS  + (size_t)SINT * HID * 2;  // 2.10 MB
  constexpr size_t OFF_H    = OFF_WPS  + (size_t)HID * SINT * 2;  // 71.30 MB
  constexpr size_t OFF_HS   = OFF_H    + (size_t)MAXSLOT * INTR * 2;  // 16.78 MB
  constexpr size_t OFF_Y    = OFF_HS   + (size_t)TOKS * SINT * 2;  // 35.65 MB
  constexpr size_t OFF_YS   = OFF_Y    + (size_t)MAXSLOT * HID * 2;  // 16.78 MB
  constexpr size_t OFF_CNT  = OFF_YS   + (size_t)TOKS * HID * 2;
  constexpr size_t OFF_OFFS = OFF_CNT  + 32;
  constexpr size_t OFF_RECE = OFF_OFFS + 64;
  constexpr size_t OFF_RECP = OFF_RECE + (size_t)TOKS * 4;
  constexpr size_t OFF_RECG = OFF_RECP + (size_t)TOKS * 4;
  constexpr size_t OFF_TOK  = OFF_RECG + (size_t)TOKS * 8;
  // total ~229 MB

  unsigned short* xb   = (unsigned short*)(ws + OFF_XB);
  unsigned short* wfcb = (unsigned short*)(ws + OFF_WFC);
  unsigned short* wpjb = (unsigned short*)(ws + OFF_WPJ);
  unsigned short* wfsb = (unsigned short*)(ws + OFF_WFS);
  unsigned short* wpsb = (unsigned short*)(ws + OFF_WPS);
  unsigned short* h    = (unsigned short*)(ws + OFF_H);
  unsigned short* hs   = (unsigned short*)(ws + OFF_HS);
  unsigned short* Y    = (unsigned short*)(ws + OFF_Y);
  unsigned short* Ys   = (unsigned short*)(ws + OFF_YS);
  int*    cnt   = (int*)(ws + OFF_CNT);
  int*    offs  = (int*)(ws + OFF_OFFS);
  int*    rec_e = (int*)(ws + OFF_RECE);
  int*    rec_p = (int*)(ws + OFF_RECP);
  float2* rec_g = (float2*)(ws + OFF_RECG);
  int*    tok   = (int*)(ws + OFF_TOK);

  hipMemsetAsync(cnt, 0, NEXP * sizeof(int), stream);

  // one fused convert for all 4 weight tensors
  k_f2bf_all<<<2048, 256, 0, stream>>>(
      wfc, wfcb, NEXP * INTR * HID / 4,
      wpj, wpjb, NEXP * HID * INTR / 4,
      wfs, wfsb, SINT * HID / 4,
      wps, wpsb, HID * SINT / 4);

  k_router<<<TOKS / 4, 256, 0, stream>>>(x, wg, xb, rec_e, rec_g);
  k_count<<<TOKS / 256, 256, 0, stream>>>(rec_e, rec_p, cnt);
  k_scan<<<1, 64, 0, stream>>>(cnt, offs);
  k_assign<<<TOKS / 256, 256, 0, stream>>>(rec_e, rec_p, offs, tok);

  // expert fc: M<=8192/expert, N=2048, K=1024 -> h (gelu)
  k_gemm<0><<<dim3(64, INTR / 128, NEXP), 256, 0, stream>>>(xb, wfcb, h, cnt, offs, tok, HID, INTR);
  // shared fc: M=8192, N=1024, K=1024 -> hs (gelu)
  k_gemm<2><<<dim3(TOKS / 128, SINT / 128, 1), 256, 0, stream>>>(xb, wfsb, hs, cnt, offs, tok, HID, SINT);
  // expert proj: N=1024, K=2048 -> Y (raw bf16, per-slot)
  k_gemm<1><<<dim3(64, HID / 128, NEXP), 256, 0, stream>>>(h, wpjb, Y, cnt, offs, tok, INTR, HID);
  // shared proj: N=1024, K=1024 -> Ys (raw bf16)
  k_gemm<3><<<dim3(TOKS / 128, HID / 128, 1), 256, 0, stream>>>(hs, wpsb, Ys, cnt, offs, tok, SINT, HID);

  // final combine: out[t] = g0*Y[s0] + g1*Y[s1] + Ys[t]
  k_combine<<<TOKS, 256, 0, stream>>>(Y, Ys, rec_e, rec_p, rec_g, offs, out);
}